// Round 6
// baseline (78.862 us; speedup 1.0000x reference)
//
#include <hip/hip_runtime.h>

#define EMB 200
#define U_DIM 32
#define T_DIM 4
#define DIM_A 32
#define NN 10
#define NSTRIPE 8
#define REGION 2048          // capacity per (type,stripe) = B/8
#define G 16                 // b's per embed group

__global__ __launch_bounds__(64) void k_init(int* __restrict__ cnt) {
    if (threadIdx.x < T_DIM * NSTRIPE) cnt[threadIdx.x] = 0;
}

// ---------- phase 1: gather+sum -> attention -> comb; striped type-scatter ----------
__global__ __launch_bounds__(1024, 4) void k_comb(
    const int* __restrict__ train_types,
    const int* __restrict__ node_neigh,
    const float* __restrict__ node_type_emb,
    const float* __restrict__ tw1,
    const float* __restrict__ tw2,
    float* __restrict__ combw,
    int* __restrict__ cnt,
    int* __restrict__ perm)
{
    __shared__ float s_nte[16][T_DIM][U_DIM];
    __shared__ int hist[T_DIM], hbase[T_DIM];

    const int tid  = threadIdx.x;
    const int wid  = tid >> 6, lane = tid & 63;
    const int u    = lane & 31, th = lane >> 5;
    const int b    = blockIdx.x * 16 + wid;
    const int s    = blockIdx.x & (NSTRIPE - 1);

    if (tid < T_DIM) hist[tid] = 0;
    __syncthreads();

    const int ty = train_types[b];
    int r = 0;
    if (lane == 0) r = atomicAdd(&hist[ty], 1);   // rank among block's waves of type ty

    const int nb = (lane < T_DIM * NN) ? node_neigh[b * T_DIM * NN + lane] : 0;

    #pragma unroll
    for (int tt = 0; tt < 2; ++tt) {
        const int t = tt * 2 + th;
        float a = 0.f;
        #pragma unroll
        for (int n = 0; n < NN; ++n) {
            const int idx = __shfl(nb, t * NN + n, 64);
            a += node_type_emb[((long)idx * T_DIM + t) * U_DIM + u];
        }
        s_nte[wid][t][u] = a;
    }

    // attention (same-wave LDS RAW; compiler inserts lgkmcnt)
    const float* tw1p = tw1 + ty * U_DIM * DIM_A;
    const float  w2   = tw2[ty * DIM_A + u];
    float sc[2];
    #pragma unroll
    for (int tt = 0; tt < 2; ++tt) {
        const int t = tt * 2 + th;
        float a1 = 0.f;
        #pragma unroll
        for (int uu = 0; uu < U_DIM; ++uu)
            a1 += s_nte[wid][t][uu] * tw1p[uu * DIM_A + u];
        float sv = tanhf(a1) * w2;
        #pragma unroll
        for (int m = 1; m < 32; m <<= 1) sv += __shfl_xor(sv, m, 64);
        sc[tt] = sv;
    }
    const float o0 = __shfl_xor(sc[0], 32, 64);
    const float o1 = __shfl_xor(sc[1], 32, 64);
    const float s0 = th ? o0    : sc[0];
    const float s1 = th ? sc[0] : o0;
    const float s2 = th ? o1    : sc[1];
    const float s3 = th ? sc[1] : o1;

    const float mx  = fmaxf(fmaxf(s0, s1), fmaxf(s2, s3));
    const float e0  = __expf(s0 - mx), e1 = __expf(s1 - mx);
    const float e2  = __expf(s2 - mx), e3 = __expf(s3 - mx);
    const float inv = 1.f / (e0 + e1 + e2 + e3);
    const float comb = (e0 * s_nte[wid][0][u] + e1 * s_nte[wid][1][u] +
                        e2 * s_nte[wid][2][u] + e3 * s_nte[wid][3][u]) * inv;
    if (lane < 32) combw[(size_t)b * 32 + u] = comb;

    // finalize scatter
    __syncthreads();
    if (tid < T_DIM) hbase[tid] = atomicAdd(&cnt[tid * NSTRIPE + s], hist[tid]);
    __syncthreads();
    if (lane == 0) perm[(ty * NSTRIPE + s) * REGION + hbase[ty] + r] = b;
}

// ---------- phase 2: 16 same-type b's per wave; comb in regs, readlane broadcast ----------
__global__ __launch_bounds__(256) void k_embed(
    const int* __restrict__ train_inputs,
    const int* __restrict__ perm,
    const int* __restrict__ cnt,
    const float* __restrict__ combw,
    const float* __restrict__ node_emb,
    const float* __restrict__ tw,
    float* __restrict__ out)
{
    const int lane = threadIdx.x & 63;
    const int wg   = blockIdx.x * 4 + (threadIdx.x >> 6);
    const int t    = wg >> 10;
    const int s    = (wg >> 7) & (NSTRIPE - 1);
    const int gi   = wg & 127;

    const int n_all = cnt[t * NSTRIPE + s];
    const int start = gi * G;
    if (start >= n_all) return;
    const int n = min(G, n_all - start);

    const int base = (t * NSTRIPE + s) * REGION + start;

    const int gl = lane >> 2;        // which group element this lane's comb regs serve
    const int q  = lane & 3;
    int bg_l = 0;
    if (gl < n) bg_l = perm[base + gl];
    const int nd_l = train_inputs[bg_l];

    float carr[8];
    *(float4*)(&carr[0]) = *(const float4*)(combw + (size_t)bg_l * 32 + q * 8);
    *(float4*)(&carr[4]) = *(const float4*)(combw + (size_t)bg_l * 32 + q * 8 + 4);

    const int c  = lane;                       // col-chunk role of this lane
    const int cc = (c < 49) ? c : 49;          // clamp for safe addresses

    const float* twp = tw + (size_t)t * U_DIM * EMB + cc * 4;

    float acc[G][4];
    #pragma unroll
    for (int g = 0; g < G; ++g) { acc[g][0] = acc[g][1] = acc[g][2] = acc[g][3] = 0.f; }

    float4 wbuf[2];
    wbuf[0] = *(const float4*)(twp);
    #pragma unroll
    for (int uu = 0; uu < U_DIM; ++uu) {
        if (uu + 1 < U_DIM) wbuf[(uu + 1) & 1] = *(const float4*)(twp + (uu + 1) * EMB);
        const float4 wv = wbuf[uu & 1];
        const int creg = __float_as_int(carr[uu & 7]);
        #pragma unroll
        for (int g = 0; g < G; ++g) {
            const float cg = __int_as_float(
                __builtin_amdgcn_readlane(creg, g * 4 + (uu >> 3)));
            acc[g][0] += cg * wv.x; acc[g][1] += cg * wv.y;
            acc[g][2] += cg * wv.z; acc[g][3] += cg * wv.w;
        }
    }

    // batch-prefetch all 16 node rows
    float4 nv[G];
    #pragma unroll
    for (int g = 0; g < G; ++g) {
        const int snd = __builtin_amdgcn_readlane(nd_l, g * 4);
        nv[g] = *(const float4*)(node_emb + (size_t)snd * EMB + cc * 4);
    }

    #pragma unroll
    for (int g = 0; g < G; ++g) {
        const int sbg = __builtin_amdgcn_readlane(bg_l, g * 4);
        const float vx = acc[g][0] + nv[g].x;
        const float vy = acc[g][1] + nv[g].y;
        const float vz = acc[g][2] + nv[g].z;
        const float vw = acc[g][3] + nv[g].w;
        float ss = (c < EMB / 4) ? (vx * vx + vy * vy + vz * vz + vw * vw) : 0.f;
        #pragma unroll
        for (int m = 1; m < 64; m <<= 1) ss += __shfl_xor(ss, m, 64);
        const float rinv = 1.f / fmaxf(sqrtf(ss), 1e-12f);
        if (g < n && c < EMB / 4) {
            float4 o = make_float4(vx * rinv, vy * rinv, vz * rinv, vw * rinv);
            *(float4*)(out + (size_t)sbg * EMB + c * 4) = o;
        }
    }
}

extern "C" void kernel_launch(void* const* d_in, const int* in_sizes, int n_in,
                              void* d_out, int out_size, void* d_ws, size_t ws_size,
                              hipStream_t stream) {
    const int*   train_inputs = (const int*)d_in[0];
    const int*   train_types  = (const int*)d_in[1];
    const int*   node_neigh   = (const int*)d_in[2];
    const float* node_emb     = (const float*)d_in[3];
    const float* node_type_e  = (const float*)d_in[4];
    const float* tw           = (const float*)d_in[5];
    const float* tw1          = (const float*)d_in[6];
    const float* tw2          = (const float*)d_in[7];
    float*       out          = (float*)d_out;

    const int B = in_sizes[0];                    // 16384

    int*   cnt   = (int*)d_ws;                    // 32 ints
    int*   perm  = cnt + T_DIM * NSTRIPE;         // 4*8*2048 = 65536 ints
    float* combw = (float*)(perm + T_DIM * NSTRIPE * REGION);  // B*32 floats, 16B-aligned

    k_init<<<1, 64, 0, stream>>>(cnt);
    k_comb<<<B / 16, 1024, 0, stream>>>(
        train_types, node_neigh, node_type_e, tw1, tw2, combw, cnt, perm);
    k_embed<<<(T_DIM * NSTRIPE * (REGION / G)) / 4, 256, 0, stream>>>(
        train_inputs, perm, cnt, combw, node_emb, tw, out);
}